// Round 1
// baseline (612.290 us; speedup 1.0000x reference)
//
#include <hip/hip_runtime.h>

// Problem constants
#define Bb 32
#define Cc 512
#define Ll 4096
#define Hh 8
#define Dd 64
#define Gg 32
#define BLt (Bb * Ll)          // 131072 rows
#define NKV 520                // 512 v cols + 8 logit cols
#define NKVPAD 640

typedef __attribute__((ext_vector_type(4))) float f32x4;
typedef __attribute__((ext_vector_type(8))) short short8;
typedef __attribute__((ext_vector_type(4))) int int4v;

union U16 { int4v v; short s[8]; };

__device__ __forceinline__ float bf2f(short s) {
    unsigned u = ((unsigned)(unsigned short)s) << 16;
    float f; __builtin_memcpy(&f, &u, 4); return f;
}
__device__ __forceinline__ short f2bf(float f) {
    unsigned u; __builtin_memcpy(&u, &f, 4);
    u = (u + 0x7FFFu + ((u >> 16) & 1u)) >> 16;
    return (short)u;
}

// LDS tile: 128 rows x 128 bytes. Fragment-interleaved k order within each
// 32-k step: 16B chunk f holds {k=4f..4f+3, k=16+4f..16+4f+3}. XOR swizzle on
// bits 4-6 by row to kill bank conflicts (applied identically write & read).
__device__ __forceinline__ int swz_off(int row, int inner) {
    return row * 128 + (inner ^ ((row & 7) << 4));
}

// ---------------- prep: fold weights ----------------
__global__ void k_prep(const float* __restrict__ Wk, const float* __restrict__ Wv,
                       const float* __restrict__ Wo, const float* __restrict__ q,
                       short* __restrict__ Wct, short* __restrict__ Wot)
{
    int bid = blockIdx.x, t = threadIdx.x;
    if (bid < NKVPAD) {
        int n = bid;
        if (n < 512) {
            for (int k = t; k < 512; k += 64)
                Wct[n * 512 + k] = f2bf(Wv[k * 512 + n]);
        } else if (n < NKV) {
            int h = n - 512;
            for (int k = t; k < 512; k += 64) {
                float acc = 0.f;
                for (int d = 0; d < 64; ++d)
                    acc += Wk[k * 512 + h * 64 + d] * q[h * 64 + d];
                Wct[n * 512 + k] = f2bf(acc * 0.125f);   // 1/sqrt(64)
            }
        } else {
            for (int k = t; k < 512; k += 64) Wct[n * 512 + k] = 0;
        }
    } else {
        int c = bid - NKVPAD;
        for (int k = t; k < 512; k += 64)
            Wot[c * 512 + k] = f2bf(Wo[k * 512 + c]);
    }
}

// ---------------- GroupNorm stats ----------------
__global__ void k_stats(const float* __restrict__ x, float* __restrict__ stats)
{
    int bg = blockIdx.x;                     // b*32 + g ; each group contiguous 65536 floats
    const float* p = x + (size_t)bg * 65536;
    int t = threadIdx.x;
    float s = 0.f, ss = 0.f;
    for (int i = t * 4; i < 65536; i += 1024) {
        f32x4 v = *(const f32x4*)(p + i);
        s  += v[0] + v[1] + v[2] + v[3];
        ss += v[0]*v[0] + v[1]*v[1] + v[2]*v[2] + v[3]*v[3];
    }
    for (int o = 32; o > 0; o >>= 1) { s += __shfl_down(s, o); ss += __shfl_down(ss, o); }
    __shared__ float red[8];
    int lane = t & 63, w = t >> 6;
    if (lane == 0) { red[w] = s; red[4 + w] = ss; }
    __syncthreads();
    if (t == 0) {
        float S  = red[0] + red[1] + red[2] + red[3];
        float SS = red[4] + red[5] + red[6] + red[7];
        float mean = S * (1.0f / 65536.0f);
        float var  = SS * (1.0f / 65536.0f) - mean * mean;
        stats[bg * 2]     = mean;
        stats[bg * 2 + 1] = rsqrtf(var + 1e-5f);
    }
}

// ---------------- normalize + transpose -> hT bf16 (BL x 512) ----------------
__global__ void k_norm_t(const float* __restrict__ x, const float* __restrict__ gamma,
                         const float* __restrict__ beta, const float* __restrict__ stats,
                         short* __restrict__ hT)
{
    __shared__ float tile[64 * 65];
    int b = blockIdx.z, c0 = blockIdx.y * 64, l0 = blockIdx.x * 64;
    int t = threadIdx.x;
    int lq = t & 15, cq = t >> 4;
    #pragma unroll
    for (int p = 0; p < 4; ++p) {
        int cl = cq + p * 16;
        int c = c0 + cl;
        float mean = stats[(b * 32 + (c >> 4)) * 2];
        float rstd = stats[(b * 32 + (c >> 4)) * 2 + 1];
        float a  = rstd * gamma[c];
        float bb = beta[c] - mean * a;
        f32x4 v = *(const f32x4*)(x + ((size_t)b << 21) + ((size_t)c << 12) + l0 + lq * 4);
        #pragma unroll
        for (int j = 0; j < 4; ++j) tile[cl * 65 + lq * 4 + j] = v[j] * a + bb;
    }
    __syncthreads();
    int ll = t >> 2, cq4 = t & 3;
    int bl = b * Ll + l0 + ll;
    short hbuf[16];
    #pragma unroll
    for (int j = 0; j < 16; ++j) hbuf[j] = f2bf(tile[(cq4 * 16 + j) * 65 + ll]);
    short8* dst = (short8*)(hT + (size_t)bl * 512 + c0 + cq4 * 16);
    dst[0] = *(short8*)&hbuf[0];
    dst[1] = *(short8*)&hbuf[8];
}

// ---------------- GEMM1: kv = hT @ [W_v | wq]  (M=BL, N=520, K=512) ----------------
__launch_bounds__(256, 2)
__global__ void k_gemm1(const short* __restrict__ hT, const short* __restrict__ Wct,
                        short* __restrict__ kv)
{
    __shared__ short sA[2][8192];
    __shared__ short sB[2][8192];
    const int t = threadIdx.x;
    const int m0 = blockIdx.y * 128;
    const int n0 = blockIdx.x * 128;
    const int lane = t & 63, wid = t >> 6;
    const int wm = wid >> 1, wn = wid & 1;
    const int g = lane >> 4, ln = lane & 15;
    const int sr = t >> 1, ksh = t & 1;

    const short* gA = hT  + (size_t)(m0 + sr) * 512 + ksh * 32;
    const short* gB = Wct + (size_t)(n0 + sr) * 512 + ksh * 32;

    f32x4 acc[4][4] = {};
    U16 ra[4], rb[4];

    auto load_tile = [&](int kt) {
        #pragma unroll
        for (int q = 0; q < 4; ++q) {
            ra[q].v = *(const int4v*)(gA + kt * 64 + q * 8);
            rb[q].v = *(const int4v*)(gB + kt * 64 + q * 8);
        }
    };
    auto write_tile = [&](int buf) {
        #pragma unroll
        for (int f = 0; f < 4; ++f) {
            U16 wa, wb;
            #pragma unroll
            for (int j = 0; j < 4; ++j) {
                wa.s[j]     = ra[f >> 1].s[(f & 1) * 4 + j];
                wa.s[4 + j] = ra[2 + (f >> 1)].s[(f & 1) * 4 + j];
                wb.s[j]     = rb[f >> 1].s[(f & 1) * 4 + j];
                wb.s[4 + j] = rb[2 + (f >> 1)].s[(f & 1) * 4 + j];
            }
            int off = swz_off(sr, ksh * 64 + f * 16);
            *(int4v*)((char*)&sA[buf][0] + off) = wa.v;
            *(int4v*)((char*)&sB[buf][0] + off) = wb.v;
        }
    };
    auto compute = [&](int buf) {
        #pragma unroll
        for (int ks = 0; ks < 2; ++ks) {
            short8 af[4], bfr[4];
            #pragma unroll
            for (int i = 0; i < 4; ++i) {
                af[i]  = *(const short8*)((const char*)&sA[buf][0] + swz_off(wm * 64 + i * 16 + ln, ks * 64 + g * 16));
                bfr[i] = *(const short8*)((const char*)&sB[buf][0] + swz_off(wn * 64 + i * 16 + ln, ks * 64 + g * 16));
            }
            #pragma unroll
            for (int mi = 0; mi < 4; ++mi)
                #pragma unroll
                for (int ni = 0; ni < 4; ++ni)
                    acc[mi][ni] = __builtin_amdgcn_mfma_f32_16x16x32_bf16(af[mi], bfr[ni], acc[mi][ni], 0, 0, 0);
        }
    };

    load_tile(0); write_tile(0); __syncthreads();
    #pragma unroll 1
    for (int kt = 0; kt < 8; ++kt) {
        if (kt < 7) load_tile(kt + 1);
        compute(kt & 1);
        if (kt < 7) write_tile((kt + 1) & 1);
        __syncthreads();
    }

    #pragma unroll
    for (int mi = 0; mi < 4; ++mi)
        #pragma unroll
        for (int ni = 0; ni < 4; ++ni)
            #pragma unroll
            for (int i = 0; i < 4; ++i) {
                int m = m0 + wm * 64 + mi * 16 + g * 4 + i;
                int n = n0 + wn * 64 + ni * 16 + ln;
                if (n < NKV) kv[(size_t)m * NKV + n] = f2bf(acc[mi][ni][i]);
            }
}

// ---------------- window softmax weights ----------------
__global__ void k_attnw(const short* __restrict__ kv, const float* __restrict__ rpe,
                        float* __restrict__ attnW)
{
    int tid = blockIdx.x * 256 + threadIdx.x;
    int bl = tid >> 3, h = tid & 7;
    int l = bl & (Ll - 1);
    float lg[3];
    #pragma unroll
    for (int j = 0; j < 3; ++j) {
        bool valid = (j == 1) || (j == 0 && l > 0) || (j == 2 && l < Ll - 1);
        lg[j] = valid ? (bf2f(kv[(size_t)(bl + j - 1) * NKV + 512 + h]) + rpe[h * 3 + j])
                      : -1e30f;
    }
    float m = fmaxf(lg[0], fmaxf(lg[1], lg[2]));
    float e0 = __expf(lg[0] - m), e1 = __expf(lg[1] - m), e2 = __expf(lg[2] - m);
    float inv = 1.0f / (e0 + e1 + e2);
    f32x4 w = { e0 * inv, e1 * inv, e2 * inv, 0.0f };
    *(f32x4*)(attnW + (size_t)bl * 32 + h * 4) = w;
}

// ------- GEMM2: out^T[c, bl] = Wo^T @ o^T, o computed on the fly; +x residual -------
__launch_bounds__(256, 2)
__global__ void k_gemm2(const short* __restrict__ Wot, const short* __restrict__ kv,
                        const float* __restrict__ attnW, const float* __restrict__ x,
                        float* __restrict__ out)
{
    __shared__ short sA[2][8192];
    __shared__ short sB[2][8192];
    const int t = threadIdx.x;
    const int m0 = blockIdx.x * 128;     // c dim
    const int n0 = blockIdx.y * 128;     // bl dim
    const int lane = t & 63, wid = t >> 6;
    const int wm = wid >> 1, wn = wid & 1;
    const int g = lane >> 4, ln = lane & 15;
    const int sr = t >> 1, ksh = t & 1;

    const short* gA = Wot + (size_t)(m0 + sr) * 512 + ksh * 32;
    const int nrow = n0 + sr;
    const int lpos = nrow & (Ll - 1);
    const int nm1 = (lpos == 0) ? nrow : nrow - 1;
    const int np1 = (lpos == Ll - 1) ? nrow : nrow + 1;
    const short* gV0 = kv + (size_t)nrow * NKV + ksh * 32;
    const short* gVm = kv + (size_t)nm1  * NKV + ksh * 32;
    const short* gVp = kv + (size_t)np1  * NKV + ksh * 32;
    const float* gW = attnW + (size_t)nrow * 32;

    f32x4 acc[4][4] = {};
    U16 ra[4], rbm[4], rb0[4], rbp[4];
    f32x4 wv;

    auto load_tile = [&](int kt) {
        #pragma unroll
        for (int q = 0; q < 4; ++q) {
            ra[q].v  = *(const int4v*)(gA  + kt * 64 + q * 8);
            rbm[q].v = *(const int4v*)(gVm + kt * 64 + q * 8);
            rb0[q].v = *(const int4v*)(gV0 + kt * 64 + q * 8);
            rbp[q].v = *(const int4v*)(gVp + kt * 64 + q * 8);
        }
        wv = *(const f32x4*)(gW + kt * 4);      // head h == kt since BK==D==64
    };
    auto write_tile = [&](int buf) {
        short ob[32];
        #pragma unroll
        for (int q = 0; q < 4; ++q)
            #pragma unroll
            for (int j = 0; j < 8; ++j) {
                float o = wv[0] * bf2f(rbm[q].s[j]) + wv[1] * bf2f(rb0[q].s[j])
                        + wv[2] * bf2f(rbp[q].s[j]);
                ob[q * 8 + j] = f2bf(o);
            }
        #pragma unroll
        for (int f = 0; f < 4; ++f) {
            U16 wa, wb;
            #pragma unroll
            for (int j = 0; j < 4; ++j) {
                wa.s[j]     = ra[f >> 1].s[(f & 1) * 4 + j];
                wa.s[4 + j] = ra[2 + (f >> 1)].s[(f & 1) * 4 + j];
                wb.s[j]     = ob[4 * f + j];
                wb.s[4 + j] = ob[16 + 4 * f + j];
            }
            int off = swz_off(sr, ksh * 64 + f * 16);
            *(int4v*)((char*)&sA[buf][0] + off) = wa.v;
            *(int4v*)((char*)&sB[buf][0] + off) = wb.v;
        }
    };
    auto compute = [&](int buf) {
        #pragma unroll
        for (int ks = 0; ks < 2; ++ks) {
            short8 af[4], bfr[4];
            #pragma unroll
            for (int i = 0; i < 4; ++i) {
                af[i]  = *(const short8*)((const char*)&sA[buf][0] + swz_off(wm * 64 + i * 16 + ln, ks * 64 + g * 16));
                bfr[i] = *(const short8*)((const char*)&sB[buf][0] + swz_off(wn * 64 + i * 16 + ln, ks * 64 + g * 16));
            }
            #pragma unroll
            for (int mi = 0; mi < 4; ++mi)
                #pragma unroll
                for (int ni = 0; ni < 4; ++ni)
                    acc[mi][ni] = __builtin_amdgcn_mfma_f32_16x16x32_bf16(af[mi], bfr[ni], acc[mi][ni], 0, 0, 0);
        }
    };

    load_tile(0); write_tile(0); __syncthreads();
    #pragma unroll 1
    for (int kt = 0; kt < 8; ++kt) {
        if (kt < 7) load_tile(kt + 1);
        compute(kt & 1);
        if (kt < 7) write_tile((kt + 1) & 1);
        __syncthreads();
    }

    #pragma unroll
    for (int mi = 0; mi < 4; ++mi)
        #pragma unroll
        for (int ni = 0; ni < 4; ++ni)
            #pragma unroll
            for (int i = 0; i < 4; ++i) {
                int c = m0 + wm * 64 + mi * 16 + g * 4 + i;
                int ng = n0 + wn * 64 + ni * 16 + ln;
                int b = ng >> 12, l = ng & (Ll - 1);
                size_t off = ((size_t)b << 21) | ((size_t)c << 12) | (size_t)l;
                out[off] = x[off] + acc[mi][ni][i];
            }
}

// ---------------- launcher ----------------
extern "C" void kernel_launch(void* const* d_in, const int* in_sizes, int n_in,
                              void* d_out, int out_size, void* d_ws, size_t ws_size,
                              hipStream_t stream)
{
    const float* x     = (const float*)d_in[0];
    const float* gamma = (const float*)d_in[1];
    const float* beta  = (const float*)d_in[2];
    const float* Wk    = (const float*)d_in[3];
    const float* Wv    = (const float*)d_in[4];
    const float* Wo    = (const float*)d_in[5];
    const float* q     = (const float*)d_in[6];
    const float* rpe   = (const float*)d_in[7];
    float* out = (float*)d_out;

    // workspace layout (bytes): total ~154.3 MB
    char* ws = (char*)d_ws;
    short* Wct   = (short*)(ws + 0);          //  655360 B (640 x 512 bf16)
    short* Wot   = (short*)(ws + 655360);     //  524288 B
    float* stats = (float*)(ws + 1179648);    //    8192 B
    float* attnW = (float*)(ws + 1187840);    // 16777216 B (BL x 32 f32)
    short* kv    = (short*)(ws + 17965056);   // 136314880 B (BL x 520 bf16)
    short* hT    = (short*)d_out;             // reuse d_out's first 128MB as scratch

    k_prep<<<1152, 64, 0, stream>>>(Wk, Wv, Wo, q, Wct, Wot);
    k_stats<<<1024, 256, 0, stream>>>(x, stats);
    k_norm_t<<<dim3(64, 8, 32), 256, 0, stream>>>(x, gamma, beta, stats, hT);
    k_gemm1<<<dim3(5, 1024), 256, 0, stream>>>(hT, Wct, kv);
    k_attnw<<<4096, 256, 0, stream>>>(kv, rpe, attnW);
    k_gemm2<<<dim3(4, 1024), 256, 0, stream>>>(Wot, kv, attnW, x, out);
}

// Round 2
// 575.085 us; speedup vs baseline: 1.0647x; 1.0647x over previous
//
#include <hip/hip_runtime.h>

// Problem constants
#define Bb 32
#define Cc 512
#define Ll 4096
#define Hh 8
#define Dd 64
#define Gg 32
#define BLt (Bb * Ll)          // 131072 rows
#define NKV 520                // 512 v cols + 8 logit cols (fallback layout)
#define NKVPAD 640

typedef __attribute__((ext_vector_type(4))) float f32x4;
typedef __attribute__((ext_vector_type(8))) short short8;
typedef __attribute__((ext_vector_type(4))) short s16x4;
typedef __attribute__((ext_vector_type(4))) int int4v;

union U16 { int4v v; short s[8]; };

__device__ __forceinline__ float bf2f(short s) {
    unsigned u = ((unsigned)(unsigned short)s) << 16;
    float f; __builtin_memcpy(&f, &u, 4); return f;
}
__device__ __forceinline__ short f2bf(float f) {
    unsigned u; __builtin_memcpy(&u, &f, 4);
    u = (u + 0x7FFFu + ((u >> 16) & 1u)) >> 16;
    return (short)u;
}

// packed-k position within a row: per 32-k block, 16B chunk f holds
// {k=f*4..f*4+3, k=16+f*4..16+f*4+3}  (MFMA 16x16x32 A/B fragment order)
__device__ __forceinline__ int kpack(int k) {
    int blk = k >> 5, r = k & 31;
    return blk * 32 + ((r & 15) >> 2) * 8 + ((r >> 4) << 2) + (r & 3);
}

// LDS tile: 128 rows x 128 bytes, XOR swizzle bits 4-6 by row.
__device__ __forceinline__ int swz_off(int row, int inner) {
    return row * 128 + (inner ^ ((row & 7) << 4));
}

__device__ __forceinline__ void gload16(const short* g, short* l) {
    __builtin_amdgcn_global_load_lds((const __attribute__((address_space(1))) unsigned int*)g,
                                     (__attribute__((address_space(3))) unsigned int*)l,
                                     16, 0, 0);
}

// ---------------- prep: fold weights ----------------
__global__ void k_prep(const float* __restrict__ Wk, const float* __restrict__ Wv,
                       const float* __restrict__ Wo, const float* __restrict__ q,
                       short* __restrict__ Wct, short* __restrict__ Wot, int packWo)
{
    int bid = blockIdx.x, t = threadIdx.x;
    if (bid < NKVPAD) {
        int n = bid;
        if (n < 512) {
            for (int k = t; k < 512; k += 64)
                Wct[n * 512 + kpack(k)] = f2bf(Wv[k * 512 + n]);
        } else if (n < NKV) {
            int h = n - 512;
            for (int k = t; k < 512; k += 64) {
                float acc = 0.f;
                for (int d = 0; d < 64; ++d)
                    acc += Wk[k * 512 + h * 64 + d] * q[h * 64 + d];
                Wct[n * 512 + kpack(k)] = f2bf(acc * 0.125f);   // 1/sqrt(64)
            }
        } else {
            for (int k = t; k < 512; k += 64) Wct[n * 512 + kpack(k)] = 0;
        }
    } else {
        int c = bid - NKVPAD;
        for (int k = t; k < 512; k += 64)
            Wot[c * 512 + (packWo ? kpack(k) : k)] = f2bf(Wo[k * 512 + c]);
    }
}

// ---------------- GroupNorm stats ----------------
__global__ void k_stats(const float* __restrict__ x, float* __restrict__ stats)
{
    int bg = blockIdx.x;                     // b*32 + g ; contiguous 65536 floats
    const float* p = x + (size_t)bg * 65536;
    int t = threadIdx.x;
    float s = 0.f, ss = 0.f;
    for (int i = t * 4; i < 65536; i += 1024) {
        f32x4 v = *(const f32x4*)(p + i);
        s  += v[0] + v[1] + v[2] + v[3];
        ss += v[0]*v[0] + v[1]*v[1] + v[2]*v[2] + v[3]*v[3];
    }
    for (int o = 32; o > 0; o >>= 1) { s += __shfl_down(s, o); ss += __shfl_down(ss, o); }
    __shared__ float red[8];
    int lane = t & 63, w = t >> 6;
    if (lane == 0) { red[w] = s; red[4 + w] = ss; }
    __syncthreads();
    if (t == 0) {
        float S  = red[0] + red[1] + red[2] + red[3];
        float SS = red[4] + red[5] + red[6] + red[7];
        float mean = S * (1.0f / 65536.0f);
        float var  = SS * (1.0f / 65536.0f) - mean * mean;
        stats[bg * 2]     = mean;
        stats[bg * 2 + 1] = rsqrtf(var + 1e-5f);
    }
}

// ------- normalize + transpose -> hT bf16 (BL x 512), packed-k layout -------
__global__ void k_norm_t(const float* __restrict__ x, const float* __restrict__ gamma,
                         const float* __restrict__ beta, const float* __restrict__ stats,
                         short* __restrict__ hT)
{
    __shared__ float tile[64 * 65];
    int b = blockIdx.z, c0 = blockIdx.y * 64, l0 = blockIdx.x * 64;
    int t = threadIdx.x;
    int lq = t & 15, cq = t >> 4;
    #pragma unroll
    for (int p = 0; p < 4; ++p) {
        int cl = cq + p * 16;
        int c = c0 + cl;
        float mean = stats[(b * 32 + (c >> 4)) * 2];
        float rstd = stats[(b * 32 + (c >> 4)) * 2 + 1];
        float a  = rstd * gamma[c];
        float bb = beta[c] - mean * a;
        f32x4 v = *(const f32x4*)(x + ((size_t)b << 21) + ((size_t)c << 12) + l0 + lq * 4);
        #pragma unroll
        for (int j = 0; j < 4; ++j) tile[cl * 65 + lq * 4 + j] = v[j] * a + bb;
    }
    __syncthreads();
    int ll = t >> 2, cq4 = t & 3;
    int bl = b * Ll + l0 + ll;
    short hbuf[16];
    #pragma unroll
    for (int j = 0; j < 16; ++j) hbuf[j] = f2bf(tile[(cq4 * 16 + j) * 65 + ll]);
    // packed write: c-base = c0 + cq4*16 (16-aligned) -> 4 x 8B pieces
    short* dst = hT + (size_t)bl * 512 + ((c0 >> 5) + (cq4 >> 1)) * 32 + ((cq4 & 1) << 2);
    #pragma unroll
    for (int jj = 0; jj < 4; ++jj) {
        s16x4 v4 = { hbuf[jj*4+0], hbuf[jj*4+1], hbuf[jj*4+2], hbuf[jj*4+3] };
        *(s16x4*)(dst + jj * 8) = v4;
    }
}

// ---------------- GEMM1: [v | logits] = hT @ [W_v | wq]  (M=BL, N=640, K=512) ----------------
// PACKED=true : writes vbuf[m][kpack(n)] (n<512) + lbuf[m][n-512]
// PACKED=false: writes kv[m*520 + n] linear (fallback)
template<bool PACKED>
__launch_bounds__(256, 2)
__global__ void k_gemm1(const short* __restrict__ A, const short* __restrict__ Bw,
                        short* __restrict__ vbuf, short* __restrict__ lbuf)
{
    __shared__ short sA[2][8192];
    __shared__ short sB[2][8192];
    const int t = threadIdx.x;
    const int m0 = blockIdx.y * 128;
    const int n0 = blockIdx.x * 128;
    const int lane = t & 63, wid = t >> 6;
    const int wm = wid >> 1, wn = wid & 1;
    const int g = lane >> 4, ln = lane & 15;

    // staging: pre-swizzled per-lane source, linear LDS dest (global_load_lds)
    const int srow = wid * 8 + (lane >> 3);                     // 0..31 (+gq*32)
    const int sinner = (((lane & 7) ^ ((lane >> 3) & 7)) << 3); // shorts
    const short* gAs = A  + (size_t)(m0 + srow) * 512 + sinner;
    const short* gBs = Bw + (size_t)(n0 + srow) * 512 + sinner;

    f32x4 acc[4][4] = {};

    auto stage = [&](int kt, int buf) {
        #pragma unroll
        for (int gq = 0; gq < 4; ++gq) {
            gload16(gAs + (size_t)gq * 32 * 512 + kt * 64, &sA[buf][gq * 2048 + wid * 512]);
            gload16(gBs + (size_t)gq * 32 * 512 + kt * 64, &sB[buf][gq * 2048 + wid * 512]);
        }
    };
    auto compute = [&](int buf) {
        #pragma unroll
        for (int ks = 0; ks < 2; ++ks) {
            short8 af[4], bfr[4];
            #pragma unroll
            for (int i = 0; i < 4; ++i) {
                af[i]  = *(const short8*)((const char*)&sA[buf][0] + swz_off(wm * 64 + i * 16 + ln, ks * 64 + g * 16));
                bfr[i] = *(const short8*)((const char*)&sB[buf][0] + swz_off(wn * 64 + i * 16 + ln, ks * 64 + g * 16));
            }
            #pragma unroll
            for (int mi = 0; mi < 4; ++mi)
                #pragma unroll
                for (int ni = 0; ni < 4; ++ni)
                    acc[mi][ni] = __builtin_amdgcn_mfma_f32_16x16x32_bf16(af[mi], bfr[ni], acc[mi][ni], 0, 0, 0);
        }
    };

    stage(0, 0);
    __syncthreads();
    #pragma unroll 1
    for (int kt = 0; kt < 8; ++kt) {
        if (kt < 7) stage(kt + 1, (kt + 1) & 1);
        compute(kt & 1);
        __syncthreads();
    }

    #pragma unroll
    for (int mi = 0; mi < 4; ++mi)
        #pragma unroll
        for (int ni = 0; ni < 4; ++ni) {
            int n = n0 + wn * 64 + ni * 16 + ln;
            #pragma unroll
            for (int i = 0; i < 4; ++i) {
                int m = m0 + wm * 64 + mi * 16 + g * 4 + i;
                short val = f2bf(acc[mi][ni][i]);
                if constexpr (PACKED) {
                    if (n < 512)      vbuf[(size_t)m * 512 + kpack(n)] = val;
                    else if (n < NKV) lbuf[(size_t)m * 8 + (n - 512)] = val;
                } else {
                    if (n < NKV) vbuf[(size_t)m * NKV + n] = val;
                }
            }
        }
}

// ------- combine: o[bl] = sum_j w_j(bl,h) * v[bl+j-1]  (packed domain) -------
__global__ void k_combine(const short* __restrict__ vbuf, const short* __restrict__ lbuf,
                          const float* __restrict__ rpe, short* __restrict__ obuf)
{
    int t = threadIdx.x;
    int bl = blockIdx.x * 16 + (t >> 4);
    int blkd = t & 15;                      // 32-k block index; head = blkd>>1
    int h = blkd >> 1;
    int l = bl & (Ll - 1);
    int bm = (l == 0) ? bl : bl - 1;
    int bp = (l == Ll - 1) ? bl : bl + 1;
    float lg0 = (l > 0)      ? bf2f(lbuf[(size_t)bm * 8 + h]) + rpe[h * 3 + 0] : -1e30f;
    float lg1 =                bf2f(lbuf[(size_t)bl * 8 + h]) + rpe[h * 3 + 1];
    float lg2 = (l < Ll - 1) ? bf2f(lbuf[(size_t)bp * 8 + h]) + rpe[h * 3 + 2] : -1e30f;
    float m = fmaxf(lg1, fmaxf(lg0, lg2));
    float e0 = (l > 0)      ? __expf(lg0 - m) : 0.f;
    float e1 =                __expf(lg1 - m);
    float e2 = (l < Ll - 1) ? __expf(lg2 - m) : 0.f;
    float inv = 1.0f / (e0 + e1 + e2);
    float w0 = e0 * inv, w1 = e1 * inv, w2 = e2 * inv;

    const short8* vm = (const short8*)(vbuf + (size_t)bm * 512 + blkd * 32);
    const short8* v0 = (const short8*)(vbuf + (size_t)bl * 512 + blkd * 32);
    const short8* vp = (const short8*)(vbuf + (size_t)bp * 512 + blkd * 32);
    short8* dst = (short8*)(obuf + (size_t)bl * 512 + blkd * 32);
    #pragma unroll
    for (int qq = 0; qq < 4; ++qq) {
        short8 a = vm[qq], b = v0[qq], c = vp[qq], r;
        #pragma unroll
        for (int j = 0; j < 8; ++j)
            r[j] = f2bf(w0 * bf2f(a[j]) + w1 * bf2f(b[j]) + w2 * bf2f(c[j]));
        dst[qq] = r;
    }
}

// ------- GEMM2 (main): out^T = Wo^T @ o^T + x, pure GEMM, packed operands -------
__launch_bounds__(256, 2)
__global__ void k_gemm2p(const short* __restrict__ Wot, const short* __restrict__ obuf,
                         const float* __restrict__ x, float* __restrict__ out)
{
    __shared__ short sA[2][8192];
    __shared__ short sB[2][8192];
    const int t = threadIdx.x;
    const int m0 = blockIdx.x * 128;     // c dim
    const int n0 = blockIdx.y * 128;     // bl dim
    const int lane = t & 63, wid = t >> 6;
    const int wm = wid >> 1, wn = wid & 1;
    const int g = lane >> 4, ln = lane & 15;

    const int srow = wid * 8 + (lane >> 3);
    const int sinner = (((lane & 7) ^ ((lane >> 3) & 7)) << 3);
    const short* gAs = Wot  + (size_t)(m0 + srow) * 512 + sinner;
    const short* gBs = obuf + (size_t)(n0 + srow) * 512 + sinner;

    f32x4 acc[4][4] = {};

    auto stage = [&](int kt, int buf) {
        #pragma unroll
        for (int gq = 0; gq < 4; ++gq) {
            gload16(gAs + (size_t)gq * 32 * 512 + kt * 64, &sA[buf][gq * 2048 + wid * 512]);
            gload16(gBs + (size_t)gq * 32 * 512 + kt * 64, &sB[buf][gq * 2048 + wid * 512]);
        }
    };
    auto compute = [&](int buf) {
        #pragma unroll
        for (int ks = 0; ks < 2; ++ks) {
            short8 af[4], bfr[4];
            #pragma unroll
            for (int i = 0; i < 4; ++i) {
                af[i]  = *(const short8*)((const char*)&sA[buf][0] + swz_off(wm * 64 + i * 16 + ln, ks * 64 + g * 16));
                bfr[i] = *(const short8*)((const char*)&sB[buf][0] + swz_off(wn * 64 + i * 16 + ln, ks * 64 + g * 16));
            }
            #pragma unroll
            for (int mi = 0; mi < 4; ++mi)
                #pragma unroll
                for (int ni = 0; ni < 4; ++ni)
                    acc[mi][ni] = __builtin_amdgcn_mfma_f32_16x16x32_bf16(af[mi], bfr[ni], acc[mi][ni], 0, 0, 0);
        }
    };

    stage(0, 0);
    __syncthreads();
    #pragma unroll 1
    for (int kt = 0; kt < 8; ++kt) {
        if (kt < 7) stage(kt + 1, (kt + 1) & 1);
        compute(kt & 1);
        __syncthreads();
    }

    #pragma unroll
    for (int mi = 0; mi < 4; ++mi)
        #pragma unroll
        for (int ni = 0; ni < 4; ++ni)
            #pragma unroll
            for (int i = 0; i < 4; ++i) {
                int c = m0 + wm * 64 + mi * 16 + g * 4 + i;
                int ng = n0 + wn * 64 + ni * 16 + ln;
                int b = ng >> 12, l = ng & (Ll - 1);
                size_t off = ((size_t)b << 21) | ((size_t)c << 12) | (size_t)l;
                out[off] = x[off] + acc[mi][ni][i];
            }
}

// ---------------- fallback path (round-1, ws too small) ----------------
__global__ void k_attnw(const short* __restrict__ kv, const float* __restrict__ rpe,
                        float* __restrict__ attnW)
{
    int tid = blockIdx.x * 256 + threadIdx.x;
    int bl = tid >> 3, h = tid & 7;
    int l = bl & (Ll - 1);
    float lg[3];
    #pragma unroll
    for (int j = 0; j < 3; ++j) {
        bool valid = (j == 1) || (j == 0 && l > 0) || (j == 2 && l < Ll - 1);
        lg[j] = valid ? (bf2f(kv[(size_t)(bl + j - 1) * NKV + 512 + h]) + rpe[h * 3 + j])
                      : -1e30f;
    }
    float m = fmaxf(lg[0], fmaxf(lg[1], lg[2]));
    float e0 = __expf(lg[0] - m), e1 = __expf(lg[1] - m), e2 = __expf(lg[2] - m);
    float inv = 1.0f / (e0 + e1 + e2);
    f32x4 w = { e0 * inv, e1 * inv, e2 * inv, 0.0f };
    *(f32x4*)(attnW + (size_t)bl * 32 + h * 4) = w;
}

__launch_bounds__(256, 2)
__global__ void k_gemm2_fused(const short* __restrict__ Wot, const short* __restrict__ kv,
                              const float* __restrict__ attnW, const float* __restrict__ x,
                              float* __restrict__ out)
{
    __shared__ short sA[2][8192];
    __shared__ short sB[2][8192];
    const int t = threadIdx.x;
    const int m0 = blockIdx.x * 128;
    const int n0 = blockIdx.y * 128;
    const int lane = t & 63, wid = t >> 6;
    const int wm = wid >> 1, wn = wid & 1;
    const int g = lane >> 4, ln = lane & 15;
    const int sr = t >> 1, ksh = t & 1;

    const short* gA = Wot + (size_t)(m0 + sr) * 512 + ksh * 32;
    const int nrow = n0 + sr;
    const int lpos = nrow & (Ll - 1);
    const int nm1 = (lpos == 0) ? nrow : nrow - 1;
    const int np1 = (lpos == Ll - 1) ? nrow : nrow + 1;
    const short* gV0 = kv + (size_t)nrow * NKV + ksh * 32;
    const short* gVm = kv + (size_t)nm1  * NKV + ksh * 32;
    const short* gVp = kv + (size_t)np1  * NKV + ksh * 32;
    const float* gW = attnW + (size_t)nrow * 32;

    f32x4 acc[4][4] = {};
    U16 ra[4], rbm[4], rb0[4], rbp[4];
    f32x4 wv;

    auto load_tile = [&](int kt) {
        #pragma unroll
        for (int qq = 0; qq < 4; ++qq) {
            ra[qq].v  = *(const int4v*)(gA  + kt * 64 + qq * 8);
            rbm[qq].v = *(const int4v*)(gVm + kt * 64 + qq * 8);
            rb0[qq].v = *(const int4v*)(gV0 + kt * 64 + qq * 8);
            rbp[qq].v = *(const int4v*)(gVp + kt * 64 + qq * 8);
        }
        wv = *(const f32x4*)(gW + kt * 4);
    };
    auto write_tile = [&](int buf) {
        short ob[32];
        #pragma unroll
        for (int qq = 0; qq < 4; ++qq)
            #pragma unroll
            for (int j = 0; j < 8; ++j) {
                float o = wv[0] * bf2f(rbm[qq].s[j]) + wv[1] * bf2f(rb0[qq].s[j])
                        + wv[2] * bf2f(rbp[qq].s[j]);
                ob[qq * 8 + j] = f2bf(o);
            }
        #pragma unroll
        for (int f = 0; f < 4; ++f) {
            U16 wa, wb;
            #pragma unroll
            for (int j = 0; j < 4; ++j) {
                wa.s[j]     = ra[f >> 1].s[(f & 1) * 4 + j];
                wa.s[4 + j] = ra[2 + (f >> 1)].s[(f & 1) * 4 + j];
                wb.s[j]     = ob[4 * f + j];
                wb.s[4 + j] = ob[16 + 4 * f + j];
            }
            int off = swz_off(sr, ksh * 64 + f * 16);
            *(int4v*)((char*)&sA[buf][0] + off) = wa.v;
            *(int4v*)((char*)&sB[buf][0] + off) = wb.v;
        }
    };
    auto compute = [&](int buf) {
        #pragma unroll
        for (int ks = 0; ks < 2; ++ks) {
            short8 af[4], bfr[4];
            #pragma unroll
            for (int i = 0; i < 4; ++i) {
                af[i]  = *(const short8*)((const char*)&sA[buf][0] + swz_off(wm * 64 + i * 16 + ln, ks * 64 + g * 16));
                bfr[i] = *(const short8*)((const char*)&sB[buf][0] + swz_off(wn * 64 + i * 16 + ln, ks * 64 + g * 16));
            }
            #pragma unroll
            for (int mi = 0; mi < 4; ++mi)
                #pragma unroll
                for (int ni = 0; ni < 4; ++ni)
                    acc[mi][ni] = __builtin_amdgcn_mfma_f32_16x16x32_bf16(af[mi], bfr[ni], acc[mi][ni], 0, 0, 0);
        }
    };

    load_tile(0); write_tile(0); __syncthreads();
    #pragma unroll 1
    for (int kt = 0; kt < 8; ++kt) {
        if (kt < 7) load_tile(kt + 1);
        compute(kt & 1);
        if (kt < 7) write_tile((kt + 1) & 1);
        __syncthreads();
    }

    #pragma unroll
    for (int mi = 0; mi < 4; ++mi)
        #pragma unroll
        for (int ni = 0; ni < 4; ++ni)
            #pragma unroll
            for (int i = 0; i < 4; ++i) {
                int c = m0 + wm * 64 + mi * 16 + g * 4 + i;
                int ng = n0 + wn * 64 + ni * 16 + ln;
                int b = ng >> 12, l = ng & (Ll - 1);
                size_t off = ((size_t)b << 21) | ((size_t)c << 12) | (size_t)l;
                out[off] = x[off] + acc[mi][ni][i];
            }
}

// ---------------- launcher ----------------
extern "C" void kernel_launch(void* const* d_in, const int* in_sizes, int n_in,
                              void* d_out, int out_size, void* d_ws, size_t ws_size,
                              hipStream_t stream)
{
    const float* x     = (const float*)d_in[0];
    const float* gamma = (const float*)d_in[1];
    const float* beta  = (const float*)d_in[2];
    const float* Wk    = (const float*)d_in[3];
    const float* Wv    = (const float*)d_in[4];
    const float* Wo    = (const float*)d_in[5];
    const float* q     = (const float*)d_in[6];
    const float* rpe   = (const float*)d_in[7];
    float* out = (float*)d_out;
    char* ws = (char*)d_ws;

    const size_t MB128 = 134217728ull;
    const size_t MAIN_WS = MB128 * 2 + 655360 + 524288 + 2097152 + 8192;

    if (ws_size >= MAIN_WS) {
        short* obuf  = (short*)(ws);
        short* vbuf  = (short*)(ws + MB128);
        short* Wct   = (short*)(ws + 2 * MB128);
        short* Wot   = (short*)(ws + 2 * MB128 + 655360);
        short* lbuf  = (short*)(ws + 2 * MB128 + 655360 + 524288);
        float* stats = (float*)(ws + 2 * MB128 + 655360 + 524288 + 2097152);
        short* hT    = (short*)d_out;          // scratch until gemm1 done

        k_prep<<<1152, 64, 0, stream>>>(Wk, Wv, Wo, q, Wct, Wot, 1);
        k_stats<<<1024, 256, 0, stream>>>(x, stats);
        k_norm_t<<<dim3(64, 8, 32), 256, 0, stream>>>(x, gamma, beta, stats, hT);
        k_gemm1<true><<<dim3(5, 1024), 256, 0, stream>>>(hT, Wct, vbuf, lbuf);
        k_combine<<<8192, 256, 0, stream>>>(vbuf, lbuf, rpe, obuf);
        k_gemm2p<<<dim3(4, 1024), 256, 0, stream>>>(Wot, obuf, x, out);
    } else {
        short* Wct   = (short*)(ws + 0);
        short* Wot   = (short*)(ws + 655360);
        float* stats = (float*)(ws + 1179648);
        float* attnW = (float*)(ws + 1187840);
        short* kv    = (short*)(ws + 17965056);
        short* hT    = (short*)d_out;

        k_prep<<<1152, 64, 0, stream>>>(Wk, Wv, Wo, q, Wct, Wot, 0);
        k_stats<<<1024, 256, 0, stream>>>(x, stats);
        k_norm_t<<<dim3(64, 8, 32), 256, 0, stream>>>(x, gamma, beta, stats, hT);
        k_gemm1<false><<<dim3(5, 1024), 256, 0, stream>>>(hT, Wct, kv, nullptr);
        k_attnw<<<4096, 256, 0, stream>>>(kv, rpe, attnW);
        k_gemm2_fused<<<dim3(4, 1024), 256, 0, stream>>>(Wot, kv, attnW, x, out);
    }
}